// Round 8
// baseline (67.187 us; speedup 1.0000x reference)
//
#include <hip/hip_runtime.h>
#include <hip/hip_bf16.h>

using f32x4 = __attribute__((ext_vector_type(4))) float;
using s16x8 = __attribute__((ext_vector_type(8))) short;

constexpr int KDIM = 768;
constexpr int NDIM = 768;
constexpr int BM = 128;
constexpr int BN = 128;
constexpr int BK = 32;
constexpr int NBN = NDIM / BN;  // 6
constexpr int NT = KDIM / BK;   // 24 k-iterations

__device__ __forceinline__ unsigned short f2bf(float f) {
    __bf16 h = (__bf16)f;       // pairs lower to v_cvt_pk_bf16_f32
    return __builtin_bit_cast(unsigned short, h);
}

__device__ __forceinline__ short sgnbf(float w) {
    unsigned u = __builtin_bit_cast(unsigned, w);
    return (w != 0.f) ? (short)(unsigned short)(0x3F80u | ((u >> 16) & 0x8000u))
                      : (short)0;
}

__device__ __forceinline__ s16x8 cvt8(float4 u, float4 v) {
    s16x8 c;
    c[0] = (short)f2bf(u.x); c[1] = (short)f2bf(u.y);
    c[2] = (short)f2bf(u.z); c[3] = (short)f2bf(u.w);
    c[4] = (short)f2bf(v.x); c[5] = (short)f2bf(v.y);
    c[6] = (short)f2bf(v.z); c[7] = (short)f2bf(v.w);
    return c;
}

// Block-contiguous fragment-ordered W: for (kt, bn), 8 KB chunk of 512 slots.
// slot = n16l*64 + lane; element j: col = bn*128+n16l*16+(lane&15),
// k = kt*32+(lane>>4)*8+j
__global__ void binarize_w(const float* __restrict__ W, unsigned short* __restrict__ Wf) {
    const int g = blockIdx.x * 256 + threadIdx.x;   // 24*6*8*64 = 73728 threads
    const int lane = g & 63;
    const int grp  = g >> 6;
    const int n16l = grp & 7;
    const int bkt  = grp >> 3;
    const int bn   = bkt % NBN;
    const int kt   = bkt / NBN;
    const int col  = bn * 128 + n16l * 16 + (lane & 15);
    const int k0   = kt * 32 + (lane >> 4) * 8;
    const float* src = W + (size_t)col * KDIM + k0;
    s16x8 r;
    #pragma unroll
    for (int j = 0; j < 8; ++j) r[j] = sgnbf(src[j]);
    *(s16x8*)(Wf + (size_t)g * 8) = r;
}

// Barrier that does NOT drain vmcnt (ds ops ordered via lgkmcnt(0)).
#define BAR_NODRAIN() do {                                        \
    asm volatile("s_waitcnt lgkmcnt(0)" ::: "memory");            \
    __builtin_amdgcn_s_barrier();                                 \
    asm volatile("" ::: "memory");                                \
} while (0)

// Octet-level bank swizzle: XOR chunk bits (slot[5:4]) into slot[2:1].
// Makes every 8-lane group of a ds_{read,write}_b128 hit 8 distinct
// bank-quads (slot mod 8 all-distinct), for both the staging writes and
// the fragment reads (derivation in journal).
__device__ __forceinline__ int swz2(int s) { return s ^ (((s >> 4) & 3) << 1); }

// LDS: fragment-ordered, logical slot = sub16*64 + lane, 16 B/slot, 8KB/buf
template<bool PRE>
__global__ __launch_bounds__(256, 4)
void binlin_mfma(const float* __restrict__ X, const float* __restrict__ W,
                 const unsigned short* __restrict__ Wf, float* __restrict__ Out) {
    __shared__ __align__(16) unsigned short As[2][512 * 8];   // 2 x 8 KB
    __shared__ __align__(16) unsigned short Bs[2][512 * 8];   // 2 x 8 KB

    const int bid = blockIdx.x;
    const int cpx = gridDim.x >> 3;                 // 1536 % 8 == 0 -> bijective
    const int swz = (bid & 7) * cpx + (bid >> 3);   // same-XCD chunks; bn fastest
    const int bm = swz / NBN;
    const int bn = swz - bm * NBN;

    const int t    = threadIdx.x;
    const int lane = t & 63;
    const int wid  = t >> 6;
    const int wm   = (wid >> 1) * 64;
    const int wn   = (wid & 1) * 64;
    const int wm16 = (wid >> 1) * 4;
    const int wn16 = (wid & 1) * 4;

    const float* Xb = X + (size_t)bm * BM * KDIM;

    // ---- A staging: thread t reads rows {t>>2, (t>>2)+64}, k-chunk (t&3)*8;
    // adjacent lane quads cover contiguous 128 B per row (proven in R6).
    const int r   = t >> 2;
    const int c8  = (t & 3) * 8;
    const float* Abase = Xb + (size_t)r * KDIM + c8;
    const int sA1 = swz2((r >> 4) * 64 + (r & 15) + 16 * (t & 3));
    const int sA2 = swz2((r >> 4) * 64 + (r & 15) + 16 * (t & 3) + 256);

    float4 aR[4];
    s16x8  bR[2];

    auto loadA = [&](int kt) {
        const float* p = Abase + kt * BK;
        aR[0] = *(const float4*)p;
        aR[1] = *(const float4*)(p + 4);
        aR[2] = *(const float4*)(p + (size_t)64 * KDIM);
        aR[3] = *(const float4*)(p + (size_t)64 * KDIM + 4);
    };
    auto writeA = [&](int buf) {
        *(s16x8*)&As[buf][(size_t)sA1 * 8] = cvt8(aR[0], aR[1]);
        *(s16x8*)&As[buf][(size_t)sA2 * 8] = cvt8(aR[2], aR[3]);
    };
    // ---- B staging: thread t owns logical slots {t, t+256} (octet-clean,
    // Wf reads stay 16B-stride coalesced)
    const int sB1 = swz2(t);
    const int sB2 = swz2(t + 256);
    auto loadB = [&](int kt) {
        if constexpr (PRE) {
            const unsigned short* q = Wf + ((size_t)(kt * NBN + bn) * 512 + t) * 8;
            bR[0] = *(const s16x8*)q;
            bR[1] = *(const s16x8*)(q + 256 * 8);
        } else {
            #pragma unroll
            for (int i = 0; i < 2; ++i) {
                const int s    = t + i * 256;
                const int col  = bn * 128 + (s >> 6) * 16 + (s & 15);
                const int k0   = kt * 32 + ((s >> 4) & 3) * 8;
                const float* wp = W + (size_t)col * KDIM + k0;
                float4 u = *(const float4*)wp;
                float4 v = *(const float4*)(wp + 4);
                s16x8 c;
                c[0] = sgnbf(u.x); c[1] = sgnbf(u.y); c[2] = sgnbf(u.z); c[3] = sgnbf(u.w);
                c[4] = sgnbf(v.x); c[5] = sgnbf(v.y); c[6] = sgnbf(v.z); c[7] = sgnbf(v.w);
                bR[i] = c;
            }
        }
    };
    auto writeB = [&](int buf) {
        *(s16x8*)&Bs[buf][(size_t)sB1 * 8] = bR[0];
        *(s16x8*)&Bs[buf][(size_t)sB2 * 8] = bR[1];
    };

    f32x4 acc[4][4] = {};

    // ---- prologue ----
    loadA(0); loadB(0);
    writeA(0); writeB(0);
    BAR_NODRAIN();

    #pragma unroll 2
    for (int kt = 0; kt < NT; ++kt) {
        const int c = kt & 1;
        const bool pf = (kt + 1 < NT);

        // issue-early: next tile's global loads (hide under MFMA below)
        if (pf) { loadA(kt + 1); loadB(kt + 1); }

        // fragments from LDS (swizzled, octet-conflict-free)
        s16x8 af[4], bf_[4];
        #pragma unroll
        for (int m = 0; m < 4; ++m)
            af[m] = *(const s16x8*)&As[c][(size_t)swz2((wm16 + m) * 64 + lane) * 8];
        #pragma unroll
        for (int n = 0; n < 4; ++n)
            bf_[n] = *(const s16x8*)&Bs[c][(size_t)swz2((wn16 + n) * 64 + lane) * 8];

        #pragma unroll
        for (int m = 0; m < 4; ++m)
            #pragma unroll
            for (int n = 0; n < 4; ++n)
                acc[m][n] = __builtin_amdgcn_mfma_f32_16x16x32_bf16(
                    af[m], bf_[n], acc[m][n], 0, 0, 0);

        // write-late into the other buffer, one barrier per iter
        if (pf) {
            writeA(c ^ 1); writeB(c ^ 1);
            BAR_NODRAIN();
        }
    }

    // ---- epilogue: C/D layout col = lane&15, row = (lane>>4)*4 + reg ----
    float* Ob = Out + (size_t)(bm * BM) * NDIM + bn * BN;
    const int lr = lane & 15;
    #pragma unroll
    for (int m = 0; m < 4; ++m) {
        const int row0 = wm + m * 16 + (lane >> 4) * 4;
        #pragma unroll
        for (int n = 0; n < 4; ++n) {
            const int col = wn + n * 16 + lr;
            #pragma unroll
            for (int rr = 0; rr < 4; ++rr)
                Ob[(size_t)(row0 + rr) * NDIM + col] = acc[m][n][rr];
        }
    }
}

extern "C" void kernel_launch(void* const* d_in, const int* in_sizes, int n_in,
                              void* d_out, int out_size, void* d_ws, size_t ws_size,
                              hipStream_t stream) {
    const float* X = (const float*)d_in[0];
    const float* W = (const float*)d_in[1];
    float* Out = (float*)d_out;
    const int M = in_sizes[0] / KDIM;                  // 32768
    const int grid = (M / BM) * NBN;                   // 1536
    const size_t need = (size_t)NDIM * KDIM * sizeof(unsigned short);  // 1.125 MB

    if (ws_size >= need) {
        unsigned short* Wf = (unsigned short*)d_ws;
        binarize_w<<<(NT * NBN * 8 * 64) / 256, 256, 0, stream>>>(W, Wf);
        binlin_mfma<true><<<grid, 256, 0, stream>>>(X, W, Wf, Out);
    } else {
        binlin_mfma<false><<<grid, 256, 0, stream>>>(X, W, nullptr, Out);
    }
}

// Round 9
// 60.905 us; speedup vs baseline: 1.1031x; 1.1031x over previous
//
#include <hip/hip_runtime.h>
#include <hip/hip_bf16.h>

using f32x4 = __attribute__((ext_vector_type(4))) float;
using s16x8 = __attribute__((ext_vector_type(8))) short;

constexpr int KDIM = 768;
constexpr int NDIM = 768;
constexpr int BM = 128;
constexpr int BN = 128;
constexpr int BK = 32;
constexpr int NBN = NDIM / BN;  // 6
constexpr int NT = KDIM / BK;   // 24 k-iterations

__device__ __forceinline__ unsigned short f2bf(float f) {
    __bf16 h = (__bf16)f;       // pairs lower to v_cvt_pk_bf16_f32
    return __builtin_bit_cast(unsigned short, h);
}

__device__ __forceinline__ short sgnbf(float w) {
    unsigned u = __builtin_bit_cast(unsigned, w);
    return (w != 0.f) ? (short)(unsigned short)(0x3F80u | ((u >> 16) & 0x8000u))
                      : (short)0;
}

__device__ __forceinline__ s16x8 cvt8(float4 u, float4 v) {
    s16x8 c;
    c[0] = (short)f2bf(u.x); c[1] = (short)f2bf(u.y);
    c[2] = (short)f2bf(u.z); c[3] = (short)f2bf(u.w);
    c[4] = (short)f2bf(v.x); c[5] = (short)f2bf(v.y);
    c[6] = (short)f2bf(v.z); c[7] = (short)f2bf(v.w);
    return c;
}

// Block-contiguous fragment-ordered W: for (kt, bn), 8 KB chunk of 512 slots.
// slot = n16l*64 + lane; element j: col = bn*128+n16l*16+(lane&15),
// k = kt*32+(lane>>4)*8+j
__global__ void binarize_w(const float* __restrict__ W, unsigned short* __restrict__ Wf) {
    const int g = blockIdx.x * 256 + threadIdx.x;   // 24*6*8*64 = 73728 threads
    const int lane = g & 63;
    const int grp  = g >> 6;
    const int n16l = grp & 7;
    const int bkt  = grp >> 3;
    const int bn   = bkt % NBN;
    const int kt   = bkt / NBN;
    const int col  = bn * 128 + n16l * 16 + (lane & 15);
    const int k0   = kt * 32 + (lane >> 4) * 8;
    const float* src = W + (size_t)col * KDIM + k0;
    s16x8 r;
    #pragma unroll
    for (int j = 0; j < 8; ++j) r[j] = sgnbf(src[j]);
    *(s16x8*)(Wf + (size_t)g * 8) = r;
}

// Barrier that does NOT drain vmcnt (ds ops ordered via lgkmcnt(0)).
#define BAR_NODRAIN() do {                                        \
    asm volatile("s_waitcnt lgkmcnt(0)" ::: "memory");            \
    __builtin_amdgcn_s_barrier();                                 \
    asm volatile("" ::: "memory");                                \
} while (0)

// LDS: fragment-ordered, slot = sub16*64 + lane, 16 B/slot, 512 slots = 8 KB/buf
// (R6 layout — unswizzled; R8 proved conflicts are off the critical path here)
template<bool PRE>
__global__ __launch_bounds__(256, 3)
void binlin_mfma(const float* __restrict__ X, const float* __restrict__ W,
                 const unsigned short* __restrict__ Wf, float* __restrict__ Out) {
    __shared__ __align__(16) unsigned short As[2][512 * 8];   // 2 x 8 KB
    __shared__ __align__(16) unsigned short Bs[2][512 * 8];   // 2 x 8 KB

    const int bid = blockIdx.x;
    const int cpx = gridDim.x >> 3;                 // 1536 % 8 == 0 -> bijective
    const int swz = (bid & 7) * cpx + (bid >> 3);   // same-XCD chunks; bn fastest
    const int bm = swz / NBN;
    const int bn = swz - bm * NBN;

    const int t    = threadIdx.x;
    const int lane = t & 63;
    const int wid  = t >> 6;
    const int wm   = (wid >> 1) * 64;
    const int wn   = (wid & 1) * 64;
    const int wm16 = (wid >> 1) * 4;
    const int wn16 = (wid & 1) * 4;

    const float* Xb = X + (size_t)bm * BM * KDIM;

    // ---- A staging: thread t reads rows {t>>2, (t>>2)+64}, k-chunk (t&3)*8;
    // adjacent lane quads cover contiguous 128 B per row (proven in R6).
    const int r   = t >> 2;
    const int c8  = (t & 3) * 8;
    const float* Abase = Xb + (size_t)r * KDIM + c8;
    const int sA1 = (r >> 4) * 64 + (r & 15) + 16 * (t & 3);
    const int sA2 = sA1 + 256;

    auto loadA = [&](int kt, float4 a[4]) {
        const float* p = Abase + kt * BK;
        a[0] = *(const float4*)p;
        a[1] = *(const float4*)(p + 4);
        a[2] = *(const float4*)(p + (size_t)64 * KDIM);
        a[3] = *(const float4*)(p + (size_t)64 * KDIM + 4);
    };
    auto writeA = [&](int buf, float4 a[4]) {
        *(s16x8*)&As[buf][(size_t)sA1 * 8] = cvt8(a[0], a[1]);
        *(s16x8*)&As[buf][(size_t)sA2 * 8] = cvt8(a[2], a[3]);
    };
    // ---- B staging: thread t owns slots {2t, 2t+1} = contiguous 32 B (R6)
    auto loadB = [&](int kt, s16x8 b[2]) {
        if constexpr (PRE) {
            const unsigned short* q = Wf + ((size_t)(kt * NBN + bn) * 512 + 2 * t) * 8;
            b[0] = *(const s16x8*)q;
            b[1] = *(const s16x8*)(q + 8);
        } else {
            #pragma unroll
            for (int i = 0; i < 2; ++i) {
                const int s    = 2 * t + i;
                const int col  = bn * 128 + (s >> 6) * 16 + (s & 15);
                const int k0   = kt * 32 + ((s >> 4) & 3) * 8;
                const float* wp = W + (size_t)col * KDIM + k0;
                float4 u = *(const float4*)wp;
                float4 v = *(const float4*)(wp + 4);
                s16x8 c;
                c[0] = sgnbf(u.x); c[1] = sgnbf(u.y); c[2] = sgnbf(u.z); c[3] = sgnbf(u.w);
                c[4] = sgnbf(v.x); c[5] = sgnbf(v.y); c[6] = sgnbf(v.z); c[7] = sgnbf(v.w);
                b[i] = c;
            }
        }
    };
    auto writeB = [&](int buf, s16x8 b[2]) {
        *(s16x8*)&Bs[buf][(size_t)(2 * t) * 8]     = b[0];
        *(s16x8*)&Bs[buf][(size_t)(2 * t + 1) * 8] = b[1];
    };

    f32x4 acc[4][4] = {};
    float4 A0[4], A1[4];
    s16x8  B0[2], B1[2];

    // ---- prologue: depth-2 ----
    loadA(0, A0); loadB(0, B0);
    loadA(1, A1); loadB(1, B1);
    writeA(0, A0); writeB(0, B0);   // waits only on tile-0 loads (counted vmcnt)
    BAR_NODRAIN();

    #pragma unroll
    for (int kt = 0; kt < NT; ++kt) {
        const int c = kt & 1;
        // set[c]  : held tile kt   (already in LDS)  -> reload with tile kt+2
        // set[c^1]: holds tile kt+1 (loaded iter kt-1) -> ds_write this iter
        float4 (&AFree)[4] = c ? A1 : A0;
        float4 (&AWr)[4]   = c ? A0 : A1;
        s16x8  (&BFree)[2] = c ? B1 : B0;
        s16x8  (&BWr)[2]   = c ? B0 : B1;

        // issue-early: tile kt+2 loads (full-iteration in-flight distance)
        if (kt + 2 < NT) { loadA(kt + 2, AFree); loadB(kt + 2, BFree); }

        // fragments from LDS (lane-linear ds_read_b128)
        s16x8 af[4], bf_[4];
        #pragma unroll
        for (int m = 0; m < 4; ++m)
            af[m] = *(const s16x8*)&As[c][(size_t)((wm16 + m) * 64 + lane) * 8];
        #pragma unroll
        for (int n = 0; n < 4; ++n)
            bf_[n] = *(const s16x8*)&Bs[c][(size_t)((wn16 + n) * 64 + lane) * 8];

        #pragma unroll
        for (int m = 0; m < 4; ++m)
            #pragma unroll
            for (int n = 0; n < 4; ++n)
                acc[m][n] = __builtin_amdgcn_mfma_f32_16x16x32_bf16(
                    af[m], bf_[n], acc[m][n], 0, 0, 0);

        // write-late: tile kt+1 (its loads finished ~1 full iter ago; the 8
        // kt+2 loads stay outstanding -> compiler emits counted vmcnt)
        if (kt + 1 < NT) {
            writeA(c ^ 1, AWr); writeB(c ^ 1, BWr);
            BAR_NODRAIN();
        }
    }

    // ---- epilogue: C/D layout col = lane&15, row = (lane>>4)*4 + reg ----
    float* Ob = Out + (size_t)(bm * BM) * NDIM + bn * BN;
    const int lr = lane & 15;
    #pragma unroll
    for (int m = 0; m < 4; ++m) {
        const int row0 = wm + m * 16 + (lane >> 4) * 4;
        #pragma unroll
        for (int n = 0; n < 4; ++n) {
            const int col = wn + n * 16 + lr;
            #pragma unroll
            for (int rr = 0; rr < 4; ++rr)
                Ob[(size_t)(row0 + rr) * NDIM + col] = acc[m][n][rr];
        }
    }
}

extern "C" void kernel_launch(void* const* d_in, const int* in_sizes, int n_in,
                              void* d_out, int out_size, void* d_ws, size_t ws_size,
                              hipStream_t stream) {
    const float* X = (const float*)d_in[0];
    const float* W = (const float*)d_in[1];
    float* Out = (float*)d_out;
    const int M = in_sizes[0] / KDIM;                  // 32768
    const int grid = (M / BM) * NBN;                   // 1536
    const size_t need = (size_t)NDIM * KDIM * sizeof(unsigned short);  // 1.125 MB

    if (ws_size >= need) {
        unsigned short* Wf = (unsigned short*)d_ws;
        binarize_w<<<(NT * NBN * 8 * 64) / 256, 256, 0, stream>>>(W, Wf);
        binlin_mfma<true><<<grid, 256, 0, stream>>>(X, W, Wf, Out);
    } else {
        binlin_mfma<false><<<grid, 256, 0, stream>>>(X, W, nullptr, Out);
    }
}